// Round 5
// baseline (173.366 us; speedup 1.0000x reference)
//
#include <hip/hip_runtime.h>
#include <hip/hip_bf16.h>

// y = (spikes @ V) @ U^T
// spikes: [4096, 16384] f32, V: [16384, 32] f32, U: [16384, 32] f32
// y: [4096, 16384] f32 (268 MB). Mask inputs are dead in the reference.
//
// Phase A (z = spikes@V) via bf16 MFMA 16x16x32, K-split into NC chunks.
// V pre-packed to bf16 B-fragment order (1 MB, cache-resident). Rolled
// depth-2 software pipeline with NAMED register slots (no full unroll ->
// bounded VGPR, no spills, loads provably issued one step-pair ahead).

#define B_DIM 4096
#define NPRE  16384
#define NPOST 16384
#define RDIM  32

#define NC     16                      // K-split chunks
#define CHUNK  (NPRE / NC)             // 1024
#define KSTEPS (CHUNK / 32)            // 32 mfma k-steps per wave

typedef __attribute__((ext_vector_type(8))) short short8;   // 8 bf16 = 4 VGPRs
typedef __attribute__((ext_vector_type(4))) float f32x4;

static __device__ __forceinline__ unsigned pack_bf2(float lo, float hi) {
    union { __hip_bfloat162 h; unsigned u; } c;
    c.h = __float22bfloat162_rn(make_float2(lo, hi));   // v_cvt_pk_bf16_f32
    return c.u;
}

// ---- V packing: vpack[((kt*2+half)*64 + lane)*8 + e] = bf16(V[kt*32+(lane>>4)*8+e][half*16+(lane&15)])
__global__ void vpack_kernel(const float* __restrict__ V, short* __restrict__ vpack)
{
    const int tid  = blockIdx.x * 256 + threadIdx.x;   // 65536 = 512 kt * 2 half * 64 lane
    const int lane = tid & 63;
    const int half = (tid >> 6) & 1;
    const int kt   = tid >> 7;
    const int n    = half * 16 + (lane & 15);
    const int k0   = kt * 32 + (lane >> 4) * 8;
    union { short8 s; short el[8]; } f;
    #pragma unroll
    for (int e = 0; e < 8; ++e) {
        union { __hip_bfloat16 h; short s; } c;
        c.h = __float2bfloat16(V[(size_t)(k0 + e) * RDIM + n]);
        f.el[e] = c.s;
    }
    *reinterpret_cast<short8*>(vpack + (size_t)tid * 8) = f.s;
}

// ---- phase A: one wave = one (16-row strip, 1024-k chunk) partial ----------
__global__ __launch_bounds__(256) void zpart_kernel(
    const float* __restrict__ spikes, const short* __restrict__ vpack,
    float* __restrict__ part)
{
    const int lane   = threadIdx.x & 63;
    const int widx   = threadIdx.x >> 6;
    const int bstrip = blockIdx.x >> 2;                 // 0..255
    const int kc     = ((blockIdx.x & 3) << 2) | widx;  // 0..15

    const int m  = lane & 15;     // A row within strip  (A: m = lane&15)
    const int kg = lane >> 4;     // k-group, 8 k each   (A: k = kg*8 + e)

    const float* arow  = spikes + (size_t)(bstrip * 16 + m) * NPRE
                                + (size_t)kc * CHUNK + kg * 8;
    const short* bbase = vpack + (size_t)(kc * KSTEPS) * 1024 + lane * 8;

    f32x4 acc0 = {0.f, 0.f, 0.f, 0.f};
    f32x4 acc1 = {0.f, 0.f, 0.f, 0.f};

    // prologue: slots for steps 0 and 1
    f32x4  al0 = *reinterpret_cast<const f32x4*>(arow);
    f32x4  ah0 = *reinterpret_cast<const f32x4*>(arow + 4);
    short8 b00 = *reinterpret_cast<const short8*>(bbase);
    short8 b01 = *reinterpret_cast<const short8*>(bbase + 512);
    f32x4  al1 = *reinterpret_cast<const f32x4*>(arow + 32);
    f32x4  ah1 = *reinterpret_cast<const f32x4*>(arow + 36);
    short8 b10 = *reinterpret_cast<const short8*>(bbase + 1024);
    short8 b11 = *reinterpret_cast<const short8*>(bbase + 1536);

    #pragma unroll 1
    for (int kt = 0; kt < KSTEPS - 2; kt += 2) {
        // step kt: consume slot0, refill with kt+2
        {
            union { short8 s; unsigned u[4]; } af;
            af.u[0] = pack_bf2(al0.x, al0.y);
            af.u[1] = pack_bf2(al0.z, al0.w);
            af.u[2] = pack_bf2(ah0.x, ah0.y);
            af.u[3] = pack_bf2(ah0.z, ah0.w);
            acc0 = __builtin_amdgcn_mfma_f32_16x16x32_bf16(af.s, b00, acc0, 0, 0, 0);
            acc1 = __builtin_amdgcn_mfma_f32_16x16x32_bf16(af.s, b01, acc1, 0, 0, 0);
        }
        al0 = *reinterpret_cast<const f32x4*>(arow + (kt + 2) * 32);
        ah0 = *reinterpret_cast<const f32x4*>(arow + (kt + 2) * 32 + 4);
        b00 = *reinterpret_cast<const short8*>(bbase + (size_t)(kt + 2) * 1024);
        b01 = *reinterpret_cast<const short8*>(bbase + (size_t)(kt + 2) * 1024 + 512);

        // step kt+1: consume slot1, refill with kt+3
        {
            union { short8 s; unsigned u[4]; } af;
            af.u[0] = pack_bf2(al1.x, al1.y);
            af.u[1] = pack_bf2(al1.z, al1.w);
            af.u[2] = pack_bf2(ah1.x, ah1.y);
            af.u[3] = pack_bf2(ah1.z, ah1.w);
            acc0 = __builtin_amdgcn_mfma_f32_16x16x32_bf16(af.s, b10, acc0, 0, 0, 0);
            acc1 = __builtin_amdgcn_mfma_f32_16x16x32_bf16(af.s, b11, acc1, 0, 0, 0);
        }
        al1 = *reinterpret_cast<const f32x4*>(arow + (kt + 3) * 32);
        ah1 = *reinterpret_cast<const f32x4*>(arow + (kt + 3) * 32 + 4);
        b10 = *reinterpret_cast<const short8*>(bbase + (size_t)(kt + 3) * 1024);
        b11 = *reinterpret_cast<const short8*>(bbase + (size_t)(kt + 3) * 1024 + 512);
    }

    // epilogue: steps KSTEPS-2, KSTEPS-1 (no further loads)
    {
        union { short8 s; unsigned u[4]; } af;
        af.u[0] = pack_bf2(al0.x, al0.y);
        af.u[1] = pack_bf2(al0.z, al0.w);
        af.u[2] = pack_bf2(ah0.x, ah0.y);
        af.u[3] = pack_bf2(ah0.z, ah0.w);
        acc0 = __builtin_amdgcn_mfma_f32_16x16x32_bf16(af.s, b00, acc0, 0, 0, 0);
        acc1 = __builtin_amdgcn_mfma_f32_16x16x32_bf16(af.s, b01, acc1, 0, 0, 0);
    }
    {
        union { short8 s; unsigned u[4]; } af;
        af.u[0] = pack_bf2(al1.x, al1.y);
        af.u[1] = pack_bf2(al1.z, al1.w);
        af.u[2] = pack_bf2(ah1.x, ah1.y);
        af.u[3] = pack_bf2(ah1.z, ah1.w);
        acc0 = __builtin_amdgcn_mfma_f32_16x16x32_bf16(af.s, b10, acc0, 0, 0, 0);
        acc1 = __builtin_amdgcn_mfma_f32_16x16x32_bf16(af.s, b11, acc1, 0, 0, 0);
    }

    // C layout: n = lane&15, m = (lane>>4)*4 + j   -> part[kc][bstrip*16+m][r]
    float* pout = part + ((size_t)kc * B_DIM + bstrip * 16) * RDIM;
    #pragma unroll
    for (int j = 0; j < 4; ++j) {
        const int row = kg * 4 + j;
        pout[row * RDIM + (lane & 15)]      = acc0[j];
        pout[row * RDIM + 16 + (lane & 15)] = acc1[j];
    }
}

// ---- z reduction: z[b][r] = sum_c part[c][b][r] ---------------------------
__global__ void zreduce_kernel(const float* __restrict__ part, float* __restrict__ z)
{
    const int idx = (blockIdx.x * blockDim.x + threadIdx.x) * 4;  // 131072 floats
    float sx = 0.f, sy = 0.f, sz = 0.f, sw = 0.f;
    #pragma unroll
    for (int c = 0; c < NC; ++c) {
        const float4 p = *reinterpret_cast<const float4*>(
            &part[(size_t)c * (B_DIM * RDIM) + idx]);
        sx += p.x; sy += p.y; sz += p.z; sw += p.w;
    }
    float4 s4; s4.x = sx; s4.y = sy; s4.z = sz; s4.w = sw;
    *reinterpret_cast<float4*>(&z[idx]) = s4;
}

// ---- phase B: y[b][j] = sum_r z[b][r] * U[j][r] ---------------------------
#define TJ 256
#define TB 64

__global__ __launch_bounds__(256) void ykernel(
    const float* __restrict__ z, const float* __restrict__ U,
    float* __restrict__ y)
{
    const int j  = blockIdx.x * TJ + threadIdx.x;
    const int b0 = blockIdx.y * TB;

    float u[RDIM];
    #pragma unroll
    for (int q = 0; q < 8; ++q) {
        const float4 v = *reinterpret_cast<const float4*>(&U[(size_t)j * RDIM + q * 4]);
        u[q * 4 + 0] = v.x; u[q * 4 + 1] = v.y; u[q * 4 + 2] = v.z; u[q * 4 + 3] = v.w;
    }

    for (int bb = 0; bb < TB; ++bb) {
        const float* zr = &z[(size_t)(b0 + bb) * RDIM];
        float a0 = 0.f, a1 = 0.f, a2 = 0.f, a3 = 0.f;
        #pragma unroll
        for (int r = 0; r < RDIM; r += 4) {
            a0 += zr[r + 0] * u[r + 0];
            a1 += zr[r + 1] * u[r + 1];
            a2 += zr[r + 2] * u[r + 2];
            a3 += zr[r + 3] * u[r + 3];
        }
        y[(size_t)(b0 + bb) * NPOST + j] = (a0 + a1) + (a2 + a3);
    }
}

extern "C" void kernel_launch(void* const* d_in, const int* in_sizes, int n_in,
                              void* d_out, int out_size, void* d_ws, size_t ws_size,
                              hipStream_t stream)
{
    const float* spikes = (const float*)d_in[0];   // [4096, 16384]
    const float* U      = (const float*)d_in[1];   // [16384, 32]
    const float* V      = (const float*)d_in[2];   // [16384, 32]

    float* y     = (float*)d_out;
    float* part  = (float*)d_out;                         // [16][4096][32] f32 = 8 MB
    short* vpack = (short*)((float*)d_out + (size_t)NC * B_DIM * RDIM);  // 1 MB after partials
    float* z     = (float*)d_ws;                          // 512 KB

    vpack_kernel<<<256, 256, 0, stream>>>(V, vpack);
    zpart_kernel<<<dim3(1024), 256, 0, stream>>>(spikes, vpack, part);
    zreduce_kernel<<<dim3((B_DIM * RDIM / 4) / 256), 256, 0, stream>>>(part, z);
    ykernel<<<dim3(NPOST / TJ, B_DIM / TB), 256, 0, stream>>>(z, U, y);
}